// Round 17
// baseline (221.173 us; speedup 1.0000x reference)
//
#include <hip/hip_runtime.h>

namespace {

constexpr int B = 64, N = 64, D = 64, E = 2 * D + 1;  // E = 129
constexpr int NBLK = 256, NTH = 512, LMAX = 3;
constexpr int MAXU = 768;   // >= ne + N (~514 for this graph)

__device__ __forceinline__ float4 f4ld(const float* p) { return *(const float4*)p; }
__device__ __forceinline__ void f4acc(float4& a, const float4 b) {
  a.x += b.x; a.y += b.y; a.z += b.z; a.w += b.w;
}

// Arrival-only grid barrier (election sync; nothing but atomics cross it).
__device__ __forceinline__ void gridbar(unsigned* set) {
  __syncthreads();
  if (threadIdx.x == 0) {
    const int g = blockIdx.x;
    unsigned* leaf = set + (size_t)(g & 7) * 16;
    unsigned* root = set + 8 * 16;
    __hip_atomic_fetch_add(leaf, 1u, __ATOMIC_RELAXED, __HIP_MEMORY_SCOPE_AGENT);
    if (g < 8) {
      while (__hip_atomic_load(leaf, __ATOMIC_RELAXED, __HIP_MEMORY_SCOPE_AGENT)
             < (unsigned)(NBLK / 8))
        __builtin_amdgcn_s_sleep(2);
      __hip_atomic_fetch_add(root, 1u, __ATOMIC_RELAXED, __HIP_MEMORY_SCOPE_AGENT);
    }
    while (__hip_atomic_load(root, __ATOMIC_RELAXED, __HIP_MEMORY_SCOPE_AGENT) < 8u)
      __builtin_amdgcn_s_sleep(2);
  }
  __syncthreads();
}

// Intra-XCD barrier: producers' plain stores are in the SHARED XCD L2 after
// vmcnt drain (write-through L1); consumers first-touch rotated buffers.
// Arrival flags via device-scope atomics. NO fences, NO cache maintenance.
__device__ __forceinline__ void xbar(unsigned* c, unsigned nblkg) {
  asm volatile("s_waitcnt vmcnt(0)" ::: "memory");
  __syncthreads();
  if (threadIdx.x == 0) {
    __hip_atomic_fetch_add(c, 1u, __ATOMIC_RELAXED, __HIP_MEMORY_SCOPE_AGENT);
    while (__hip_atomic_load(c, __ATOMIC_RELAXED, __HIP_MEMORY_SCOPE_AGENT) < nblkg)
      __builtin_amdgcn_s_sleep(2);
  }
  __syncthreads();
}

// LDS map: [0,32K) catT (P2) / ewL (prep) / aTw (P1); [32K,48K) wuC; 48K+ tables
constexpr int OF_WU    = 32768;
constexpr int OF_TB    = 49152;
constexpr int OF_NBR4  = OF_TB;           // 1024
constexpr int OF_DEG   = OF_TB + 1024;
constexpr int OF_CW    = OF_TB + 1280;
constexpr int OF_CNT   = OF_TB + 1536;
constexpr int OF_RB    = OF_TB + 1792;
constexpr int OF_NE    = OF_TB + 2304;
constexpr int OF_EI    = OF_TB + 2320;    // 2048
constexpr int OF_NFULL = OF_TB + 4368;    // 4096
constexpr int POOLSZ   = 57856;

__global__ __launch_bounds__(NTH) void k_fused(
    const float* __restrict__ x,   // [B][N][D]
    const float* __restrict__ ew,  // [N][N]
    const float* __restrict__ Wm,  // [L][N][N][E][D]
    const float* __restrict__ bm,  // [L][N][N][D]
    const float* __restrict__ Wu,  // [L][2D][D]
    const float* __restrict__ bu,  // [L][D]
    const float* __restrict__ Wo,  // [D][D]
    const float* __restrict__ bo,  // [D]
    float* __restrict__ out,       // [B][D]
    char* __restrict__ ws, int L)
{
  // counters region (memset 8KB each launch)
  unsigned* bar     = (unsigned*)ws;            // tree barrier, 144u
  unsigned* xcdcnt  = (unsigned*)(ws + 1024);   // 8 slots, stride 16u
  unsigned* grpctr  = (unsigned*)(ws + 2048);
  unsigned* xcd2grp = (unsigned*)(ws + 2112);   // 8 slots, stride 16u
  unsigned* gbar    = (unsigned*)(ws + 4096);   // [8 grp][8 inst], stride 16u
  char* p = ws + 8192;
  float* sbuf0 = (float*)p; p += (size_t)B * N * D * 4;
  float* sbuf1 = (float*)p; p += (size_t)B * N * D * 4;
  float* baseG = (float*)p; p += (size_t)LMAX * 8 * N * D * 4;
  float* sw1G  = (float*)p; p += (size_t)LMAX * 8 * N * D * D * 4;
  float* msgB  = (float*)p;   // [L][8][MAXU][64][64]

  __shared__ __align__(16) char pool[POOLSZ];
  float (*aTw)[72] = (float(*)[72])pool;                // [8][72], P1 only
  uint4* nbr4L = (uint4*)(pool + OF_NBR4);
  float* degL  = (float*)(pool + OF_DEG);
  float* cwL   = (float*)(pool + OF_CW);
  int*   cntL  = (int*)(pool + OF_CNT);
  int*   rbL   = (int*)(pool + OF_RB);
  int*   neL   = (int*)(pool + OF_NE);
  unsigned short* eiL = (unsigned short*)(pool + OF_EI);
  unsigned char* nfullL = (unsigned char*)(pool + OF_NFULL);
  __shared__ int shI[5];  // xcd, rank, grp, nblkg, K

  const int t = threadIdx.x;

  // ---- election: per-XCD rank + group claim ----
  if (t == 0) {
    unsigned xcd = 0;
    asm volatile("s_getreg_b32 %0, hwreg(HW_REG_XCC_ID)" : "=s"(xcd));
    xcd &= 7u;
    unsigned r = __hip_atomic_fetch_add(xcdcnt + (size_t)xcd * 16, 1u,
                                        __ATOMIC_RELAXED, __HIP_MEMORY_SCOPE_AGENT);
    if (r == 0u) {
      unsigned gp = __hip_atomic_fetch_add(grpctr, 1u, __ATOMIC_RELAXED,
                                           __HIP_MEMORY_SCOPE_AGENT);
      __hip_atomic_fetch_add(xcd2grp + (size_t)xcd * 16, gp + 1u,
                             __ATOMIC_RELAXED, __HIP_MEMORY_SCOPE_AGENT);
    }
    shI[0] = (int)xcd; shI[1] = (int)r;
  }

  // ---- prep: adjacency tables, redundant per block (read-only ew) ----
  {
    float* ewL = (float*)pool;  // 16KB overlay
#pragma unroll
    for (int r = 0; r < 2; ++r)
      ((float4*)ewL)[r * NTH + t] = ((const float4*)ew)[r * NTH + t];
    __syncthreads();
    if (t < 64) {
      float rowsum = 0.f; int rc = 0;
      for (int j = 0; j < N; ++j) {
        const float v = ewL[t * N + j];
        rowsum += v; rc += (v > 0.f) ? 1 : 0;
      }
      int pre = rc;
#pragma unroll
      for (int off = 1; off < 64; off <<= 1) {
        int v = __shfl_up(pre, off, 64);
        if (t >= off) pre += v;
      }
      const int base = pre - rc;
      rbL[t] = base;
      unsigned long long lo = 0ull, hi = 0ull; int c = 0;
      for (int j = 0; j < N; ++j) {
        const float v = ewL[t * N + j];
        if (v > 0.f) {
          eiL[base + c] = (unsigned short)((t << 6) | j);
          if (c < 8)       lo |= (unsigned long long)j << (c * 8);
          else if (c < 16) hi |= (unsigned long long)j << ((c - 8) * 8);
          nfullL[t * 64 + c] = (unsigned char)j;
          ++c;
        }
      }
      uint4 w4;
      w4.x = (unsigned)lo; w4.y = (unsigned)(lo >> 32);
      w4.z = (unsigned)hi; w4.w = (unsigned)(hi >> 32);
      nbr4L[t] = w4; cntL[t] = c; degL[t] = (float)c;
      float tot = rowsum;
#pragma unroll
      for (int off = 32; off >= 1; off >>= 1) tot += __shfl_xor(tot, off, 64);
      cwL[t] = rowsum / (tot + 1e-8f);
      if (t == 63) *neL = base + rc;
    }
    __syncthreads();
  }
  const int ne = *neL;

  gridbar(bar);  // all elections complete
  if (t == 0) {
    const int xcd = shI[0];
    shI[2] = (int)__hip_atomic_load(xcd2grp + (size_t)xcd * 16, __ATOMIC_RELAXED,
                                    __HIP_MEMORY_SCOPE_AGENT) - 1;
    shI[3] = (int)__hip_atomic_load(xcdcnt + (size_t)xcd * 16, __ATOMIC_RELAXED,
                                    __HIP_MEMORY_SCOPE_AGENT);
    shI[4] = (int)__hip_atomic_load(grpctr, __ATOMIC_RELAXED,
                                    __HIP_MEMORY_SCOPE_AGENT);
  }
  __syncthreads();
  const int rank = shI[1], grp = shI[2], nblkg = shI[3], K = shI[4];
  const int bLo = grp * B / K, bHi = (grp + 1) * B / K, nb = bHi - bLo;

  // sw1/base unit: full W1-sum (+w*W3+bm base) for (layer lw, node i)
  auto sw1unit = [&](int lw, int i) {
    float4 a0 = {0,0,0,0}, a1 = {0,0,0,0}, bacc = {0,0,0,0};
    const int ci = cntL[i];
    for (int c2 = 0; c2 < ci; ++c2) {
      const int j2 = nfullL[i * 64 + c2];
      const float* Wp = Wm + ((size_t)((lw * N + i) * N + j2)) * (E * D);
      f4acc(a0, f4ld(Wp + (size_t)(0 * NTH + t) * 4));
      f4acc(a1, f4ld(Wp + (size_t)(1 * NTH + t) * 4));
      if (t < 16) {
        const float w = ew[i * N + j2];
        const float4 w3 = f4ld(Wp + 2 * D * D + t * 4);
        const float4 bv = f4ld(bm + (((size_t)lw * N + i) * N + j2) * D + t * 4);
        bacc.x += w * w3.x + bv.x; bacc.y += w * w3.y + bv.y;
        bacc.z += w * w3.z + bv.z; bacc.w += w * w3.w + bv.w;
      }
    }
    float* dstw = sw1G + (((size_t)lw * 8 + grp) * N + i) * (D * D);
    *(float4*)(dstw + (size_t)(0 * NTH + t) * 4) = a0;
    *(float4*)(dstw + (size_t)(1 * NTH + t) * 4) = a1;
    if (t < 16)
      *(float4*)(baseG + (((size_t)lw * 8 + grp) * N + i) * D + t * 4) = bacc;
  };

  // ---- P0: sw1/base for layer 0 (group-local) ----
  for (int un = rank; un < N; un += nblkg) sw1unit(0, un);
  xbar(gbar + (size_t)(grp * 8 + 0) * 16, (unsigned)nblkg);

  for (int l = 0; l < L; ++l) {
    const float* scur = (l == 0) ? x : ((l == 1) ? sbuf0 : sbuf1);
    float* sout = (l == 0) ? sbuf0 : sbuf1;   // rotated: never rewritten
    float* msgG = msgB + ((size_t)l * 8 + grp) * MAXU * (64 * 64);
    const bool LAST = (l == L - 1);

    // ===== P1: edge + self GEMMs; wave = batch, lane = d (no block syncs) ====
    {
      const int wv = t >> 6, d = t & 63;
      const int U = ne + N;
      for (int u = rank; u < U; u += nblkg) {
        const bool self = (u >= ne);
        int j; const float* wsrc; const float* basep = nullptr;
        if (self) {
          const int i = u - ne;
          j = i;
          wsrc  = sw1G + (((size_t)l * 8 + grp) * N + i) * (D * D);
          basep = baseG + (((size_t)l * 8 + grp) * N + i) * D;
        } else {
          const int e = eiL[u];
          j = e & 63;
          wsrc = Wm + ((size_t)((l * N + (e >> 6)) * N + j)) * (E * D) + (size_t)D * D;
        }
        const float bval = basep ? basep[d] : 0.0f;
        for (int bb = wv; bb < nb; bb += 8) {
          aTw[wv][d] = scur[((size_t)((bLo + bb) * N + j)) * D + d];
          float acc = bval;
#pragma unroll 16
          for (int k = 0; k < 64; ++k)
            acc += aTw[wv][k] * wsrc[(size_t)k * 64 + d];
          msgG[((size_t)u * 64 + bb) * 64 + d] = acc;
        }
      }
    }
    xbar(gbar + (size_t)(grp * 8 + 1 + 2 * l) * 16, (unsigned)nblkg);

    // ===== P2: per-batch update+scan (+readout) || sw1 for l+1 ============
    {
      float (*catT)[64] = (float(*)[64])pool;          // 32KB
      float* wuC = (float*)(pool + OF_WU);             // 16KB chunk
      const float* Wul = Wu + (size_t)l * 2 * D * D;
      const float* bul = bu + (size_t)l * D;

      for (int b2 = rank; b2 < nb; b2 += nblkg) {
        const int b = bLo + b2;
        __syncthreads();  // previous iteration's sb/catT dead
        {
          const int ii = t >> 3, q = t & 7;
          const int cI = cntL[ii], rb = rbL[ii];
          float4 a4[2];
          const float* pself = msgG + ((size_t)(ne + ii) * 64 + b2) * 64 + q * 8;
          a4[0] = f4ld(pself); a4[1] = f4ld(pself + 4);
          for (int e2 = 0; e2 < cI; ++e2) {
            const float* pm = msgG + ((size_t)(rb + e2) * 64 + b2) * 64 + q * 8;
            f4acc(a4[0], f4ld(pm)); f4acc(a4[1], f4ld(pm + 4));
          }
          const float* ps = scur + ((size_t)(b * N + ii)) * D + q * 8;
          const float4 v0 = f4ld(ps), v1 = f4ld(ps + 4);
          const int k0 = q * 8;
          catT[k0 + 0][ii] = v0.x; catT[k0 + 1][ii] = v0.y;
          catT[k0 + 2][ii] = v0.z; catT[k0 + 3][ii] = v0.w;
          catT[k0 + 4][ii] = v1.x; catT[k0 + 5][ii] = v1.y;
          catT[k0 + 6][ii] = v1.z; catT[k0 + 7][ii] = v1.w;
          catT[D + k0 + 0][ii] = a4[0].x; catT[D + k0 + 1][ii] = a4[0].y;
          catT[D + k0 + 2][ii] = a4[0].z; catT[D + k0 + 3][ii] = a4[0].w;
          catT[D + k0 + 4][ii] = a4[1].x; catT[D + k0 + 5][ii] = a4[1].y;
          catT[D + k0 + 6][ii] = a4[1].z; catT[D + k0 + 7][ii] = a4[1].w;
        }
#pragma unroll
        for (int r = 0; r < 2; ++r)
          *(float4*)(wuC + (size_t)(r * NTH + t) * 4) =
              f4ld(Wul + (size_t)(r * NTH + t) * 4);
        __syncthreads();

        const int td = t & 15, tr = t >> 4;
        float acc[2][4];
        {
          const float4 bv = f4ld(bul + td * 4);
#pragma unroll
          for (int r = 0; r < 2; ++r) {
            acc[r][0] = bv.x; acc[r][1] = bv.y;
            acc[r][2] = bv.z; acc[r][3] = bv.w;
          }
        }
#pragma unroll 4
        for (int k = 0; k < 64; ++k) {
          const float2 a  = *(const float2*)&catT[k][tr * 2];
          const float4 wv = f4ld(wuC + k * D + td * 4);
          const float ar[2] = {a.x, a.y};
          const float wc[4] = {wv.x, wv.y, wv.z, wv.w};
#pragma unroll
          for (int r = 0; r < 2; ++r)
#pragma unroll
            for (int c2 = 0; c2 < 4; ++c2) acc[r][c2] += ar[r] * wc[c2];
        }
        __syncthreads();
#pragma unroll
        for (int r = 0; r < 2; ++r)
          *(float4*)(wuC + (size_t)(r * NTH + t) * 4) =
              f4ld(Wul + (size_t)64 * D + (size_t)(r * NTH + t) * 4);
        __syncthreads();
#pragma unroll 4
        for (int k = 0; k < 64; ++k) {
          const float2 a  = *(const float2*)&catT[64 + k][tr * 2];
          const float4 wv = f4ld(wuC + k * D + td * 4);
          const float ar[2] = {a.x, a.y};
          const float wc[4] = {wv.x, wv.y, wv.z, wv.w};
#pragma unroll
          for (int r = 0; r < 2; ++r)
#pragma unroll
            for (int c2 = 0; c2 < 4; ++c2) acc[r][c2] += ar[r] * wc[c2];
        }
#pragma unroll
        for (int r = 0; r < 2; ++r)
#pragma unroll
          for (int c2 = 0; c2 < 4; ++c2)
            acc[r][c2] = 0.9f * acc[r][c2] + 0.1f * catT[td * 4 + c2][tr * 2 + r];
        __syncthreads();
        float (*sb)[65] = (float(*)[65])pool;
#pragma unroll
        for (int r = 0; r < 2; ++r)
#pragma unroll
          for (int c2 = 0; c2 < 4; ++c2)
            sb[tr * 2 + r][td * 4 + c2] = acc[r][c2];
        __syncthreads();

        if (t < 64) {
          const int d = t;
          uint4 w = nbr4L[0];
          int c = cntL[0];
          float dg = degL[0];
          for (int ii = 0; ii < N; ++ii) {
            uint4 wn = w; int cn = c; float dgn = dg;
            if (ii < N - 1) { wn = nbr4L[ii + 1]; cn = cntL[ii + 1]; dgn = degL[ii + 1]; }
            const unsigned wd[4] = {w.x, w.y, w.z, w.w};
            float nbv = 0.0f;
#pragma unroll
            for (int q = 0; q < 8; ++q) {
              const int idx = (int)((wd[q >> 2] >> ((q & 3) * 8)) & 63u);
              const float v = sb[idx][d];
              nbv += (q < c) ? v : 0.0f;
            }
            if (c > 8) {
#pragma unroll
              for (int q = 8; q < 16; ++q) {
                const int idx = (int)((wd[q >> 2] >> ((q & 3) * 8)) & 63u);
                const float v = sb[idx][d];
                nbv += (q < c) ? v : 0.0f;
              }
              for (int q = 16; q < c; ++q) nbv += sb[nfullL[ii * 64 + q]][d];
            }
            const float avg = nbv / fmaxf(dg, 1.0f);
            const float cur = sb[ii][d];
            sb[ii][d] = (dg > 0.0f) ? (0.95f * cur + 0.05f * avg) : cur;
            w = wn; c = cn; dg = dgn;
          }
          if (LAST) {
            float gg = 0.0f;
            for (int i2 = 0; i2 < N; ++i2) gg += cwL[i2] * sb[i2][d];
            float o = bo[d];
            for (int k2 = 0; k2 < D; ++k2) o += __shfl(gg, k2, 64) * Wo[k2 * D + d];
            out[(size_t)b * D + d] = o;
          }
        }
        if (!LAST) {
          __syncthreads();
          const int ii = t >> 3, q = t & 7;
          float* ps = sout + ((size_t)(b * N + ii)) * D + q * 8;
          float4 v0, v1;
          v0.x = sb[ii][q * 8 + 0]; v0.y = sb[ii][q * 8 + 1];
          v0.z = sb[ii][q * 8 + 2]; v0.w = sb[ii][q * 8 + 3];
          v1.x = sb[ii][q * 8 + 4]; v1.y = sb[ii][q * 8 + 5];
          v1.z = sb[ii][q * 8 + 6]; v1.w = sb[ii][q * 8 + 7];
          *(float4*)ps = v0;
          *(float4*)(ps + 4) = v1;
        }
      }
      if (!LAST) {
        const int s0 = (nblkg > nb) ? nb : 0;
        const int m  = (nblkg > nb) ? (nblkg - nb) : nblkg;
        const int rr = rank - s0;
        if (rr >= 0)
          for (int un = rr; un < N; un += m) sw1unit(l + 1, un);
      }
    }
    if (!LAST) xbar(gbar + (size_t)(grp * 8 + 2 + 2 * l) * 16, (unsigned)nblkg);
  }
}

}  // namespace

extern "C" void kernel_launch(void* const* d_in, const int* in_sizes, int n_in,
                              void* d_out, int out_size, void* d_ws, size_t ws_size,
                              hipStream_t stream)
{
  const float* x  = (const float*)d_in[0];
  const float* ew = (const float*)d_in[1];
  const float* Wm = (const float*)d_in[2];
  const float* bm = (const float*)d_in[3];
  const float* Wu = (const float*)d_in[4];
  const float* bu = (const float*)d_in[5];
  const float* Wo = (const float*)d_in[6];
  const float* bo = (const float*)d_in[7];
  float* out = (float*)d_out;

  int L = in_sizes[2] / (N * N * E * D);  // = 3
  if (L > LMAX) L = LMAX;

  hipMemsetAsync(d_ws, 0, 8192, stream);  // zero election + barrier counters
  k_fused<<<NBLK, NTH, 0, stream>>>(x, ew, Wm, bm, Wu, bu, Wo, bo, out,
                                    (char*)d_ws, L);
}